// Round 9
// baseline (387.675 us; speedup 1.0000x reference)
//
#include <hip/hip_runtime.h>

#define NN 100000
#define NE 1600000
#define NG 64
#define HIDC 128
#define INC 9
#define OUTC 2
#define BSH 9                       // bucket = node >> 9 (512 nodes/bucket)
#define NBK ((NN + 511) / 512)      // 196
#define EPB 4096                    // edges per phase-A block
#define NBLKA ((NE + EPB - 1) / EPB)
#define CAP 12288                   // per-bucket staging capacity (mean 8163, +45 sigma)

typedef unsigned int u32;

// staging record: (local_col[9] << 17) | row[17]   (NN=100000 < 2^17)
#define PACK_REC(lc, r) (((u32)(lc) << 17) | (u32)(r))
#define REC_LC(v) ((v) >> 17)
#define REC_ROW(v) ((v) & 0x1FFFFu)

// ---- bf16 pack/unpack (round-to-nearest-even), 2 feats per u32 (lo=even feat) ----
__device__ inline float bf_lo(u32 u) { return __uint_as_float(u << 16); }
__device__ inline float bf_hi(u32 u) { return __uint_as_float(u & 0xFFFF0000u); }
__device__ inline u32 f2bf(float x) {
    u32 u = __float_as_uint(x);
    return (u + 0x7FFFu + ((u >> 16) & 1u)) >> 16;
}
__device__ inline u32 packbf(float a, float b) { return f2bf(a) | (f2bf(b) << 16); }

// ---------------- bucketed CSR build ----------------
__global__ void k_zero196(int* bcnt) {
    int t = threadIdx.x;
    if (t < NBK) bcnt[t] = 0;
}

// phase A: block-aggregated scatter into fixed-capacity bucket staging
__global__ __launch_bounds__(256) void k_bscatter2(const int* __restrict__ row,
                                                   const int* __restrict__ col,
                                                   int* bcnt, u32* __restrict__ staging) {
    __shared__ u32 srec[EPB];   // 16 KB packed records
    __shared__ u32 sbkt[EPB];   // 16 KB bucket ids
    __shared__ int hist[NBK];
    __shared__ int base[NBK];
    int t = threadIdx.x;
    long e0 = (long)blockIdx.x * EPB;
    int n = (NE - e0 < EPB) ? (int)(NE - e0) : EPB;
    for (int i = t; i < n; i += 256) {
        u32 c = col[e0 + i];
        u32 r = row[e0 + i];
        srec[i] = PACK_REC(c & 511u, r);
        sbkt[i] = c >> BSH;
    }
    if (t < NBK) hist[t] = 0;
    __syncthreads();
    for (int i = t; i < n; i += 256) atomicAdd(&hist[sbkt[i]], 1);
    __syncthreads();
    if (t < NBK) {
        int h = hist[t];
        base[t] = h ? atomicAdd(&bcnt[t], h) : 0;  // one global atomic per (block,bucket)
        hist[t] = 0;                               // reuse as local cursor
    }
    __syncthreads();
    for (int i = t; i < n; i += 256) {
        int b = sbkt[i];
        int p = atomicAdd(&hist[b], 1) + base[b];
        if (p < CAP) staging[(long)b * CAP + p] = srec[i];  // clamp: statistically impossible
    }
}

// scan bucket counts -> csr output bases
__global__ __launch_bounds__(256) void k_bscan(const int* __restrict__ bcnt,
                                               int* __restrict__ bbase,
                                               int* __restrict__ offsets) {
    __shared__ int lds[256];
    int t = threadIdx.x;
    int v = (t < NBK) ? bcnt[t] : 0;
    lds[t] = v;
    __syncthreads();
    for (int d = 1; d < 256; d <<= 1) {
        int u = (t >= d) ? lds[t - d] : 0;
        __syncthreads();
        lds[t] += u;
        __syncthreads();
    }
    if (t < NBK) bbase[t] = lds[t] - v;  // exclusive
    if (t == 0) offsets[NN] = NE;
}

// phase B: one block per bucket: local count -> scan -> offsets/dinv -> local scatter
__global__ __launch_bounds__(256) void k_bcsr(const u32* __restrict__ staging,
                                              const int* __restrict__ bcnt,
                                              const int* __restrict__ bbase,
                                              int* __restrict__ offsets,
                                              float* __restrict__ dinv,
                                              int* __restrict__ csr_src) {
    __shared__ int cnt[512];
    __shared__ int cur[512];
    __shared__ int sc[256];
    int b = blockIdx.x, t = threadIdx.x;
    int nb0 = b << BSH;
    int nodes = NN - nb0 < 512 ? NN - nb0 : 512;
    int ne_b = bcnt[b];
    long s0b = (long)b * CAP;
    int e0 = bbase[b];
    cnt[t] = 0;
    cnt[t + 256] = 0;
    __syncthreads();
    for (int e = t; e < ne_b; e += 256)
        atomicAdd(&cnt[REC_LC(staging[s0b + e])], 1);
    __syncthreads();
    int c0 = cnt[2 * t], c1 = cnt[2 * t + 1];
    int s = c0 + c1;
    sc[t] = s;
    __syncthreads();
    for (int d = 1; d < 256; d <<= 1) {
        int u = (t >= d) ? sc[t - d] : 0;
        __syncthreads();
        sc[t] += u;
        __syncthreads();
    }
    int ex = sc[t] - s;
    cur[2 * t] = ex;
    cur[2 * t + 1] = ex + c0;
    if (2 * t < nodes) {
        offsets[nb0 + 2 * t] = e0 + ex;
        dinv[nb0 + 2 * t] = rsqrtf((float)(c0 + 1));
    }
    if (2 * t + 1 < nodes) {
        offsets[nb0 + 2 * t + 1] = e0 + ex + c0;
        dinv[nb0 + 2 * t + 1] = rsqrtf((float)(c1 + 1));
    }
    __syncthreads();
    for (int e = t; e < ne_b; e += 256) {
        u32 r = staging[s0b + e];
        int p = atomicAdd(&cur[REC_LC(r)], 1);
        csr_src[e0 + p] = (int)REC_ROW(r);
    }
}

// ---------------- layer-1 dense: Ap = bf16( (x@W1) * dinv ) ----------------
__global__ __launch_bounds__(256) void k_xw1(const float* __restrict__ x,
                                             const float* __restrict__ W1,
                                             const float* __restrict__ dinv,
                                             u32* __restrict__ Ap2) {
    int tid = threadIdx.x;
    int i = blockIdx.x * 4 + (tid >> 6);
    int j = tid & 63;
    if (i >= NN) return;
    float acc0 = 0.f, acc1 = 0.f;
#pragma unroll
    for (int k = 0; k < INC; ++k) {
        float xv = x[i * INC + k];
        acc0 += xv * W1[k * HIDC + 2 * j];
        acc1 += xv * W1[k * HIDC + 2 * j + 1];
    }
    float di = dinv[i];
    Ap2[(long)i * 64 + j] = packbf(acc0 * di, acc1 * di);
}

// ---------------- gather: B[i] = bf16( dinv[i] * (Ap[i] + sum Ap[src]) ) ----------------
// one 64-lane wave per node; 8-deep unrolled row loads for latency hiding
__global__ __launch_bounds__(256) void k_gather(const u32* __restrict__ Ap2,
                                                const int* __restrict__ csr_src,
                                                const int* __restrict__ offsets,
                                                const float* __restrict__ dinv,
                                                u32* __restrict__ B2) {
    int i = (blockIdx.x * 256 + threadIdx.x) >> 6;
    if (i >= NN) return;
    int lane = threadIdx.x & 63;
    long base = (long)i * 64 + lane;
    u32 a = Ap2[base];
    float acc0 = bf_lo(a), acc1 = bf_hi(a);
    int beg = offsets[i], end = offsets[i + 1];
    int e = beg;
    for (; e + 8 <= end; e += 8) {
        int s0 = csr_src[e + 0], s1 = csr_src[e + 1], s2 = csr_src[e + 2], s3 = csr_src[e + 3];
        int s4 = csr_src[e + 4], s5 = csr_src[e + 5], s6 = csr_src[e + 6], s7 = csr_src[e + 7];
        u32 v0 = Ap2[(long)s0 * 64 + lane];
        u32 v1 = Ap2[(long)s1 * 64 + lane];
        u32 v2 = Ap2[(long)s2 * 64 + lane];
        u32 v3 = Ap2[(long)s3 * 64 + lane];
        u32 v4 = Ap2[(long)s4 * 64 + lane];
        u32 v5 = Ap2[(long)s5 * 64 + lane];
        u32 v6 = Ap2[(long)s6 * 64 + lane];
        u32 v7 = Ap2[(long)s7 * 64 + lane];
        acc0 += ((bf_lo(v0) + bf_lo(v1)) + (bf_lo(v2) + bf_lo(v3))) +
                ((bf_lo(v4) + bf_lo(v5)) + (bf_lo(v6) + bf_lo(v7)));
        acc1 += ((bf_hi(v0) + bf_hi(v1)) + (bf_hi(v2) + bf_hi(v3))) +
                ((bf_hi(v4) + bf_hi(v5)) + (bf_hi(v6) + bf_hi(v7)));
    }
    for (; e + 2 <= end; e += 2) {
        int s0 = csr_src[e], s1 = csr_src[e + 1];
        u32 v0 = Ap2[(long)s0 * 64 + lane];
        u32 v1 = Ap2[(long)s1 * 64 + lane];
        acc0 += bf_lo(v0) + bf_lo(v1);
        acc1 += bf_hi(v0) + bf_hi(v1);
    }
    for (; e < end; ++e) {
        u32 v = Ap2[(long)csr_src[e] * 64 + lane];
        acc0 += bf_lo(v);
        acc1 += bf_hi(v);
    }
    float di = dinv[i];
    B2[base] = packbf(acc0 * di, acc1 * di);
}

// ---------------- layer-2 dense: h=relu(B+b1); Ap = bf16((h@W2)*dinv) ----------------
// 128 nodes/block, 256 threads; thread tile = 4 nodes x 16 cols.
// hs broadcast reads; W2 read from global (L1/L2-resident 64KB).
__global__ __launch_bounds__(256) void k_layer2(const u32* __restrict__ B2,
                                                const float* __restrict__ b1,
                                                const float* __restrict__ W2,
                                                const float* __restrict__ dinv,
                                                u32* __restrict__ Ap2) {
    __shared__ float hs[128][HIDC];  // 64 KB -> 2 blocks/CU
    int t = threadIdx.x;
    int nb = blockIdx.x * 128;
    int j = t & 63;
    float bb0 = b1[2 * j], bb1 = b1[2 * j + 1];
    for (int n = t >> 6; n < 128; n += 4) {
        int node = nb + n;
        u32 u = (node < NN) ? B2[(long)node * 64 + j] : 0u;
        float h0 = bf_lo(u) + bb0;
        float h1 = bf_hi(u) + bb1;
        hs[n][2 * j] = h0 > 0.f ? h0 : 0.f;
        hs[n][2 * j + 1] = h1 > 0.f ? h1 : 0.f;
    }
    __syncthreads();
    int cg = t & 7, ng = t >> 3;
    int n0 = ng * 4;
    const float4* W4 = (const float4*)W2;  // 32 float4 per k-row
    float acc[4][16] = {};
#pragma unroll 2
    for (int k = 0; k < HIDC; ++k) {
        float4 w0 = W4[k * 32 + cg * 4 + 0];
        float4 w1 = W4[k * 32 + cg * 4 + 1];
        float4 w2 = W4[k * 32 + cg * 4 + 2];
        float4 w3 = W4[k * 32 + cg * 4 + 3];
        float a0 = hs[n0 + 0][k], a1 = hs[n0 + 1][k];
        float a2 = hs[n0 + 2][k], a3 = hs[n0 + 3][k];
#pragma unroll
        for (int r = 0; r < 4; ++r) {
            float ar = (r == 0) ? a0 : (r == 1) ? a1 : (r == 2) ? a2 : a3;
            acc[r][0] += ar * w0.x;  acc[r][1] += ar * w0.y;  acc[r][2] += ar * w0.z;  acc[r][3] += ar * w0.w;
            acc[r][4] += ar * w1.x;  acc[r][5] += ar * w1.y;  acc[r][6] += ar * w1.z;  acc[r][7] += ar * w1.w;
            acc[r][8] += ar * w2.x;  acc[r][9] += ar * w2.y;  acc[r][10] += ar * w2.z; acc[r][11] += ar * w2.w;
            acc[r][12] += ar * w3.x; acc[r][13] += ar * w3.y; acc[r][14] += ar * w3.z; acc[r][15] += ar * w3.w;
        }
    }
#pragma unroll
    for (int r = 0; r < 4; ++r) {
        int node = nb + n0 + r;
        if (node < NN) {
            float di = dinv[node];
            uint4 oa, ob;
            oa.x = packbf(acc[r][0] * di, acc[r][1] * di);
            oa.y = packbf(acc[r][2] * di, acc[r][3] * di);
            oa.z = packbf(acc[r][4] * di, acc[r][5] * di);
            oa.w = packbf(acc[r][6] * di, acc[r][7] * di);
            ob.x = packbf(acc[r][8] * di, acc[r][9] * di);
            ob.y = packbf(acc[r][10] * di, acc[r][11] * di);
            ob.z = packbf(acc[r][12] * di, acc[r][13] * di);
            ob.w = packbf(acc[r][14] * di, acc[r][15] * di);
            // row = 64 u32 = 16 uint4 per node (R8 bug: used *8)
            ((uint4*)Ap2)[(long)node * 16 + cg * 2 + 0] = oa;
            ((uint4*)Ap2)[(long)node * 16 + cg * 2 + 1] = ob;
        }
    }
}

// ---------------- pooling ----------------
__global__ void k_pool_init(float* pooled, float* cnt) {
    int i = blockIdx.x * 256 + threadIdx.x;
    if (i < NG * HIDC) pooled[i] = 0.f;
    if (i < NG) cnt[i] = 0.f;
}

__global__ __launch_bounds__(64) void k_pool(const u32* __restrict__ B2,
                                             const float* __restrict__ b2,
                                             const int* __restrict__ batch,
                                             float* pooled, float* cnt) {
    int f = threadIdx.x;
    int start = blockIdx.x * 64;
    int end = start + 64 < NN ? start + 64 : NN;
    float bb0 = b2[2 * f], bb1 = b2[2 * f + 1];
    float s0 = 0.f, s1 = 0.f;
    int gcur = -1, cl = 0;
    for (int i = start; i < end; ++i) {
        int g = batch[i];
        if (g != gcur) {
            if (gcur >= 0) {
                unsafeAtomicAdd(&pooled[gcur * HIDC + 2 * f], s0);
                unsafeAtomicAdd(&pooled[gcur * HIDC + 2 * f + 1], s1);
                if (f == 0) unsafeAtomicAdd(&cnt[gcur], (float)cl);
            }
            gcur = g; s0 = s1 = 0.f; cl = 0;
        }
        u32 u = B2[(long)i * 64 + f];
        float h0 = bf_lo(u) + bb0;
        float h1 = bf_hi(u) + bb1;
        s0 += h0 > 0.f ? h0 : 0.f;
        s1 += h1 > 0.f ? h1 : 0.f;
        cl++;
    }
    if (gcur >= 0) {
        unsafeAtomicAdd(&pooled[gcur * HIDC + 2 * f], s0);
        unsafeAtomicAdd(&pooled[gcur * HIDC + 2 * f + 1], s1);
        if (f == 0) unsafeAtomicAdd(&cnt[gcur], (float)cl);
    }
}

// ---------------- head ----------------
__global__ __launch_bounds__(128) void k_final(const float* __restrict__ pooled,
                                               const float* __restrict__ cnt,
                                               const float* __restrict__ Wc,
                                               const float* __restrict__ bc,
                                               float* __restrict__ out) {
    __shared__ float v0s[HIDC], v1s[HIDC];
    int g = blockIdx.x, f = threadIdx.x;
    float c = cnt[g]; c = c > 1.f ? c : 1.f;
    float val = pooled[g * HIDC + f] / c;
    v0s[f] = val * Wc[f * OUTC + 0];
    v1s[f] = val * Wc[f * OUTC + 1];
    __syncthreads();
    if (f < 2) {
        const float* arr = (f == 0) ? v0s : v1s;
        float s = 0.f;
        for (int k = 0; k < HIDC; ++k) s += arr[k];
        out[g * OUTC + f] = s + bc[f];
    }
}

extern "C" void kernel_launch(void* const* d_in, const int* in_sizes, int n_in,
                              void* d_out, int out_size, void* d_ws, size_t ws_size,
                              hipStream_t stream) {
    const float* x     = (const float*)d_in[0];
    const int*   ei    = (const int*)d_in[1];
    const int*   batch = (const int*)d_in[2];
    const float* W1    = (const float*)d_in[3];
    const float* b1    = (const float*)d_in[4];
    const float* W2    = (const float*)d_in[5];
    const float* b2    = (const float*)d_in[6];
    const float* Wc    = (const float*)d_in[7];
    const float* bc    = (const float*)d_in[8];
    float* out = (float*)d_out;

    char* ws = (char*)d_ws;
    size_t off = 0;
    auto alloc = [&](size_t bytes) { void* p = ws + off; off += (bytes + 255) / 256 * 256; return p; };
    u32*   Ap2     = (u32*)alloc((size_t)NN * 64 * 4);
    u32*   B2      = (u32*)alloc((size_t)NN * 64 * 4);
    float* dinv    = (float*)alloc((size_t)NN * 4);
    int*   offsets = (int*)alloc((size_t)(NN + 1) * 4);
    int*   csr_src = (int*)alloc((size_t)NE * 4);
    u32*   staging = (u32*)alloc((size_t)NBK * CAP * 4);
    int*   bcnt    = (int*)alloc((size_t)NBK * 4);
    int*   bbase   = (int*)alloc((size_t)NBK * 4);
    float* pooled  = (float*)alloc((size_t)NG * HIDC * 4);
    float* cnt     = (float*)alloc((size_t)NG * 4);

    const int* row = ei;
    const int* col = ei + NE;

    // bucketed CSR build (by target), single pass over edges + local sort
    k_zero196<<<1, 256, 0, stream>>>(bcnt);
    k_bscatter2<<<NBLKA, 256, 0, stream>>>(row, col, bcnt, staging);
    k_bscan<<<1, 256, 0, stream>>>(bcnt, bbase, offsets);
    k_bcsr<<<NBK, 256, 0, stream>>>(staging, bcnt, bbase, offsets, dinv, csr_src);

    // layer 1
    k_xw1<<<(NN + 3) / 4, 256, 0, stream>>>(x, W1, dinv, Ap2);
    k_gather<<<(NN * 64 + 255) / 256, 256, 0, stream>>>(Ap2, csr_src, offsets, dinv, B2);

    // layer 2
    k_layer2<<<(NN + 127) / 128, 256, 0, stream>>>(B2, b1, W2, dinv, Ap2);
    k_gather<<<(NN * 64 + 255) / 256, 256, 0, stream>>>(Ap2, csr_src, offsets, dinv, B2);

    // pool + head
    k_pool_init<<<(NG * HIDC + 255) / 256, 256, 0, stream>>>(pooled, cnt);
    k_pool<<<(NN + 63) / 64, 64, 0, stream>>>(B2, b2, batch, pooled, cnt);
    k_final<<<NG, 128, 0, stream>>>(pooled, cnt, Wc, bc, out);
}

// Round 10
// 311.314 us; speedup vs baseline: 1.2453x; 1.2453x over previous
//
#include <hip/hip_runtime.h>

#define NN 100000
#define NE 1600000
#define NG 64
#define HIDC 128
#define INC 9
#define OUTC 2
#define BSH 9                       // bucket = node >> 9 (512 nodes/bucket)
#define NBK ((NN + 511) / 512)      // 196
#define EPB 4096                    // edges per phase-A block
#define NBLKA ((NE + EPB - 1) / EPB)
#define CAP 12288                   // per-bucket staging capacity (mean 8163, +45 sigma)

typedef unsigned int u32;

// staging record: (local_col[9] << 17) | row[17]   (NN=100000 < 2^17)
#define PACK_REC(lc, r) (((u32)(lc) << 17) | (u32)(r))
#define REC_LC(v) ((v) >> 17)
#define REC_ROW(v) ((v) & 0x1FFFFu)

// ---- bf16 pack/unpack (round-to-nearest-even), 2 feats per u32 (lo=even feat) ----
__device__ inline float bf_lo(u32 u) { return __uint_as_float(u << 16); }
__device__ inline float bf_hi(u32 u) { return __uint_as_float(u & 0xFFFF0000u); }
__device__ inline u32 f2bf(float x) {
    u32 u = __float_as_uint(x);
    return (u + 0x7FFFu + ((u >> 16) & 1u)) >> 16;
}
__device__ inline u32 packbf(float a, float b) { return f2bf(a) | (f2bf(b) << 16); }

// ---------------- bucketed CSR build ----------------
__global__ void k_zero196(int* bcnt) {
    int t = threadIdx.x;
    if (t < NBK) bcnt[t] = 0;
}

// phase A: block-aggregated scatter into fixed-capacity bucket staging
__global__ __launch_bounds__(256) void k_bscatter2(const int* __restrict__ row,
                                                   const int* __restrict__ col,
                                                   int* bcnt, u32* __restrict__ staging) {
    __shared__ u32 srec[EPB];   // 16 KB packed records
    __shared__ u32 sbkt[EPB];   // 16 KB bucket ids
    __shared__ int hist[NBK];
    __shared__ int base[NBK];
    int t = threadIdx.x;
    long e0 = (long)blockIdx.x * EPB;
    int n = (NE - e0 < EPB) ? (int)(NE - e0) : EPB;
    for (int i = t; i < n; i += 256) {
        u32 c = col[e0 + i];
        u32 r = row[e0 + i];
        srec[i] = PACK_REC(c & 511u, r);
        sbkt[i] = c >> BSH;
    }
    if (t < NBK) hist[t] = 0;
    __syncthreads();
    for (int i = t; i < n; i += 256) atomicAdd(&hist[sbkt[i]], 1);
    __syncthreads();
    if (t < NBK) {
        int h = hist[t];
        base[t] = h ? atomicAdd(&bcnt[t], h) : 0;  // one global atomic per (block,bucket)
        hist[t] = 0;                               // reuse as local cursor
    }
    __syncthreads();
    for (int i = t; i < n; i += 256) {
        int b = sbkt[i];
        int p = atomicAdd(&hist[b], 1) + base[b];
        if (p < CAP) staging[(long)b * CAP + p] = srec[i];  // clamp: statistically impossible
    }
}

// scan bucket counts -> csr output bases
__global__ __launch_bounds__(256) void k_bscan(const int* __restrict__ bcnt,
                                               int* __restrict__ bbase,
                                               int* __restrict__ offsets) {
    __shared__ int lds[256];
    int t = threadIdx.x;
    int v = (t < NBK) ? bcnt[t] : 0;
    lds[t] = v;
    __syncthreads();
    for (int d = 1; d < 256; d <<= 1) {
        int u = (t >= d) ? lds[t - d] : 0;
        __syncthreads();
        lds[t] += u;
        __syncthreads();
    }
    if (t < NBK) bbase[t] = lds[t] - v;  // exclusive
    if (t == 0) offsets[NN] = NE;
}

// phase B: one block per bucket: local count -> scan -> offsets/dinv -> local scatter
__global__ __launch_bounds__(256) void k_bcsr(const u32* __restrict__ staging,
                                              const int* __restrict__ bcnt,
                                              const int* __restrict__ bbase,
                                              int* __restrict__ offsets,
                                              float* __restrict__ dinv,
                                              int* __restrict__ csr_src) {
    __shared__ int cnt[512];
    __shared__ int cur[512];
    __shared__ int sc[256];
    int b = blockIdx.x, t = threadIdx.x;
    int nb0 = b << BSH;
    int nodes = NN - nb0 < 512 ? NN - nb0 : 512;
    int ne_b = bcnt[b];
    long s0b = (long)b * CAP;
    int e0 = bbase[b];
    cnt[t] = 0;
    cnt[t + 256] = 0;
    __syncthreads();
    for (int e = t; e < ne_b; e += 256)
        atomicAdd(&cnt[REC_LC(staging[s0b + e])], 1);
    __syncthreads();
    int c0 = cnt[2 * t], c1 = cnt[2 * t + 1];
    int s = c0 + c1;
    sc[t] = s;
    __syncthreads();
    for (int d = 1; d < 256; d <<= 1) {
        int u = (t >= d) ? sc[t - d] : 0;
        __syncthreads();
        sc[t] += u;
        __syncthreads();
    }
    int ex = sc[t] - s;
    cur[2 * t] = ex;
    cur[2 * t + 1] = ex + c0;
    if (2 * t < nodes) {
        offsets[nb0 + 2 * t] = e0 + ex;
        dinv[nb0 + 2 * t] = rsqrtf((float)(c0 + 1));
    }
    if (2 * t + 1 < nodes) {
        offsets[nb0 + 2 * t + 1] = e0 + ex + c0;
        dinv[nb0 + 2 * t + 1] = rsqrtf((float)(c1 + 1));
    }
    __syncthreads();
    for (int e = t; e < ne_b; e += 256) {
        u32 r = staging[s0b + e];
        int p = atomicAdd(&cur[REC_LC(r)], 1);
        csr_src[e0 + p] = (int)REC_ROW(r);
    }
}

// ---------------- layer-1 dense: Ap = bf16( (x@W1) * dinv ) ----------------
__global__ __launch_bounds__(256) void k_xw1(const float* __restrict__ x,
                                             const float* __restrict__ W1,
                                             const float* __restrict__ dinv,
                                             u32* __restrict__ Ap2) {
    int tid = threadIdx.x;
    int i = blockIdx.x * 4 + (tid >> 6);
    int j = tid & 63;
    if (i >= NN) return;
    float acc0 = 0.f, acc1 = 0.f;
#pragma unroll
    for (int k = 0; k < INC; ++k) {
        float xv = x[i * INC + k];
        acc0 += xv * W1[k * HIDC + 2 * j];
        acc1 += xv * W1[k * HIDC + 2 * j + 1];
    }
    float di = dinv[i];
    Ap2[(long)i * 64 + j] = packbf(acc0 * di, acc1 * di);
}

// ---------------- gather: B[i] = bf16( dinv[i] * (Ap[i] + sum Ap[src]) ) ----------------
// one 64-lane wave per node; 8-deep unrolled row loads for latency hiding
__global__ __launch_bounds__(256) void k_gather(const u32* __restrict__ Ap2,
                                                const int* __restrict__ csr_src,
                                                const int* __restrict__ offsets,
                                                const float* __restrict__ dinv,
                                                u32* __restrict__ B2) {
    int i = (blockIdx.x * 256 + threadIdx.x) >> 6;
    if (i >= NN) return;
    int lane = threadIdx.x & 63;
    long base = (long)i * 64 + lane;
    u32 a = Ap2[base];
    float acc0 = bf_lo(a), acc1 = bf_hi(a);
    int beg = offsets[i], end = offsets[i + 1];
    int e = beg;
    for (; e + 8 <= end; e += 8) {
        int s0 = csr_src[e + 0], s1 = csr_src[e + 1], s2 = csr_src[e + 2], s3 = csr_src[e + 3];
        int s4 = csr_src[e + 4], s5 = csr_src[e + 5], s6 = csr_src[e + 6], s7 = csr_src[e + 7];
        u32 v0 = Ap2[(long)s0 * 64 + lane];
        u32 v1 = Ap2[(long)s1 * 64 + lane];
        u32 v2 = Ap2[(long)s2 * 64 + lane];
        u32 v3 = Ap2[(long)s3 * 64 + lane];
        u32 v4 = Ap2[(long)s4 * 64 + lane];
        u32 v5 = Ap2[(long)s5 * 64 + lane];
        u32 v6 = Ap2[(long)s6 * 64 + lane];
        u32 v7 = Ap2[(long)s7 * 64 + lane];
        acc0 += ((bf_lo(v0) + bf_lo(v1)) + (bf_lo(v2) + bf_lo(v3))) +
                ((bf_lo(v4) + bf_lo(v5)) + (bf_lo(v6) + bf_lo(v7)));
        acc1 += ((bf_hi(v0) + bf_hi(v1)) + (bf_hi(v2) + bf_hi(v3))) +
                ((bf_hi(v4) + bf_hi(v5)) + (bf_hi(v6) + bf_hi(v7)));
    }
    for (; e + 2 <= end; e += 2) {
        int s0 = csr_src[e], s1 = csr_src[e + 1];
        u32 v0 = Ap2[(long)s0 * 64 + lane];
        u32 v1 = Ap2[(long)s1 * 64 + lane];
        acc0 += bf_lo(v0) + bf_lo(v1);
        acc1 += bf_hi(v0) + bf_hi(v1);
    }
    for (; e < end; ++e) {
        u32 v = Ap2[(long)csr_src[e] * 64 + lane];
        acc0 += bf_lo(v);
        acc1 += bf_hi(v);
    }
    float di = dinv[i];
    B2[base] = packbf(acc0 * di, acc1 * di);
}

// ---------------- layer-2 dense: h=relu(B+b1); Ap = bf16((h@W2)*dinv) ----------------
// R7-proven version: 64 nodes/block; thread tile = 4 nodes x (4+4) cols;
// W2 staged in LDS k-tiles; hs padded [64][129] -> conflict-free.
__global__ __launch_bounds__(256) void k_layer2(const u32* __restrict__ B2,
                                                const float* __restrict__ b1,
                                                const float* __restrict__ W2,
                                                const float* __restrict__ dinv,
                                                u32* __restrict__ Ap2) {
    __shared__ float hs[64][HIDC + 1];
    __shared__ float W2s[32][HIDC];
    int t = threadIdx.x;
    int nb = blockIdx.x * 64;
    int j = t & 63;
    float bb0 = b1[2 * j], bb1 = b1[2 * j + 1];
    for (int n = t >> 6; n < 64; n += 4) {
        int node = nb + n;
        u32 u = (node < NN) ? B2[(long)node * 64 + j] : 0u;
        float h0 = bf_lo(u) + bb0;
        float h1 = bf_hi(u) + bb1;
        hs[n][2 * j] = h0 > 0.f ? h0 : 0.f;
        hs[n][2 * j + 1] = h1 > 0.f ? h1 : 0.f;
    }
    int cg = t & 15, ng = t >> 4;
    int n0 = ng * 4, c0 = cg * 4;
    float acc[4][8] = {};
    for (int kt = 0; kt < 4; ++kt) {
        __syncthreads();
        for (int idx = t; idx < 1024; idx += 256)
            ((float4*)W2s)[idx] = ((const float4*)W2)[kt * 1024 + idx];
        __syncthreads();
#pragma unroll 8
        for (int k = 0; k < 32; ++k) {
            int kk = kt * 32 + k;
            float a0 = hs[n0 + 0][kk], a1 = hs[n0 + 1][kk];
            float a2 = hs[n0 + 2][kk], a3 = hs[n0 + 3][kk];
            float4 w0 = *(const float4*)&W2s[k][c0];
            float4 w1 = *(const float4*)&W2s[k][c0 + 64];
            acc[0][0] += a0 * w0.x; acc[0][1] += a0 * w0.y; acc[0][2] += a0 * w0.z; acc[0][3] += a0 * w0.w;
            acc[0][4] += a0 * w1.x; acc[0][5] += a0 * w1.y; acc[0][6] += a0 * w1.z; acc[0][7] += a0 * w1.w;
            acc[1][0] += a1 * w0.x; acc[1][1] += a1 * w0.y; acc[1][2] += a1 * w0.z; acc[1][3] += a1 * w0.w;
            acc[1][4] += a1 * w1.x; acc[1][5] += a1 * w1.y; acc[1][6] += a1 * w1.z; acc[1][7] += a1 * w1.w;
            acc[2][0] += a2 * w0.x; acc[2][1] += a2 * w0.y; acc[2][2] += a2 * w0.z; acc[2][3] += a2 * w0.w;
            acc[2][4] += a2 * w1.x; acc[2][5] += a2 * w1.y; acc[2][6] += a2 * w1.z; acc[2][7] += a2 * w1.w;
            acc[3][0] += a3 * w0.x; acc[3][1] += a3 * w0.y; acc[3][2] += a3 * w0.z; acc[3][3] += a3 * w0.w;
            acc[3][4] += a3 * w1.x; acc[3][5] += a3 * w1.y; acc[3][6] += a3 * w1.z; acc[3][7] += a3 * w1.w;
        }
    }
#pragma unroll
    for (int r = 0; r < 4; ++r) {
        int node = nb + n0 + r;
        if (node < NN) {
            float di = dinv[node];
            uint2 oa, ob;
            oa.x = packbf(acc[r][0] * di, acc[r][1] * di);
            oa.y = packbf(acc[r][2] * di, acc[r][3] * di);
            ob.x = packbf(acc[r][4] * di, acc[r][5] * di);
            ob.y = packbf(acc[r][6] * di, acc[r][7] * di);
            ((uint2*)Ap2)[(long)node * 32 + cg] = oa;       // cols c0..c0+3
            ((uint2*)Ap2)[(long)node * 32 + 16 + cg] = ob;  // cols 64+c0..+3
        }
    }
}

// ---------------- pooling ----------------
__global__ void k_pool_init(float* pooled, float* cnt) {
    int i = blockIdx.x * 256 + threadIdx.x;
    if (i < NG * HIDC) pooled[i] = 0.f;
    if (i < NG) cnt[i] = 0.f;
}

__global__ __launch_bounds__(64) void k_pool(const u32* __restrict__ B2,
                                             const float* __restrict__ b2,
                                             const int* __restrict__ batch,
                                             float* pooled, float* cnt) {
    int f = threadIdx.x;
    int start = blockIdx.x * 64;
    int end = start + 64 < NN ? start + 64 : NN;
    float bb0 = b2[2 * f], bb1 = b2[2 * f + 1];
    float s0 = 0.f, s1 = 0.f;
    int gcur = -1, cl = 0;
    for (int i = start; i < end; ++i) {
        int g = batch[i];
        if (g != gcur) {
            if (gcur >= 0) {
                unsafeAtomicAdd(&pooled[gcur * HIDC + 2 * f], s0);
                unsafeAtomicAdd(&pooled[gcur * HIDC + 2 * f + 1], s1);
                if (f == 0) unsafeAtomicAdd(&cnt[gcur], (float)cl);
            }
            gcur = g; s0 = s1 = 0.f; cl = 0;
        }
        u32 u = B2[(long)i * 64 + f];
        float h0 = bf_lo(u) + bb0;
        float h1 = bf_hi(u) + bb1;
        s0 += h0 > 0.f ? h0 : 0.f;
        s1 += h1 > 0.f ? h1 : 0.f;
        cl++;
    }
    if (gcur >= 0) {
        unsafeAtomicAdd(&pooled[gcur * HIDC + 2 * f], s0);
        unsafeAtomicAdd(&pooled[gcur * HIDC + 2 * f + 1], s1);
        if (f == 0) unsafeAtomicAdd(&cnt[gcur], (float)cl);
    }
}

// ---------------- head ----------------
__global__ __launch_bounds__(128) void k_final(const float* __restrict__ pooled,
                                               const float* __restrict__ cnt,
                                               const float* __restrict__ Wc,
                                               const float* __restrict__ bc,
                                               float* __restrict__ out) {
    __shared__ float v0s[HIDC], v1s[HIDC];
    int g = blockIdx.x, f = threadIdx.x;
    float c = cnt[g]; c = c > 1.f ? c : 1.f;
    float val = pooled[g * HIDC + f] / c;
    v0s[f] = val * Wc[f * OUTC + 0];
    v1s[f] = val * Wc[f * OUTC + 1];
    __syncthreads();
    if (f < 2) {
        const float* arr = (f == 0) ? v0s : v1s;
        float s = 0.f;
        for (int k = 0; k < HIDC; ++k) s += arr[k];
        out[g * OUTC + f] = s + bc[f];
    }
}

extern "C" void kernel_launch(void* const* d_in, const int* in_sizes, int n_in,
                              void* d_out, int out_size, void* d_ws, size_t ws_size,
                              hipStream_t stream) {
    const float* x     = (const float*)d_in[0];
    const int*   ei    = (const int*)d_in[1];
    const int*   batch = (const int*)d_in[2];
    const float* W1    = (const float*)d_in[3];
    const float* b1    = (const float*)d_in[4];
    const float* W2    = (const float*)d_in[5];
    const float* b2    = (const float*)d_in[6];
    const float* Wc    = (const float*)d_in[7];
    const float* bc    = (const float*)d_in[8];
    float* out = (float*)d_out;

    char* ws = (char*)d_ws;
    size_t off = 0;
    auto alloc = [&](size_t bytes) { void* p = ws + off; off += (bytes + 255) / 256 * 256; return p; };
    u32*   Ap2     = (u32*)alloc((size_t)NN * 64 * 4);
    u32*   B2      = (u32*)alloc((size_t)NN * 64 * 4);
    float* dinv    = (float*)alloc((size_t)NN * 4);
    int*   offsets = (int*)alloc((size_t)(NN + 1) * 4);
    int*   csr_src = (int*)alloc((size_t)NE * 4);
    u32*   staging = (u32*)alloc((size_t)NBK * CAP * 4);
    int*   bcnt    = (int*)alloc((size_t)NBK * 4);
    int*   bbase   = (int*)alloc((size_t)NBK * 4);
    float* pooled  = (float*)alloc((size_t)NG * HIDC * 4);
    float* cnt     = (float*)alloc((size_t)NG * 4);

    const int* row = ei;
    const int* col = ei + NE;

    // bucketed CSR build (by target), single pass over edges + local sort
    k_zero196<<<1, 256, 0, stream>>>(bcnt);
    k_bscatter2<<<NBLKA, 256, 0, stream>>>(row, col, bcnt, staging);
    k_bscan<<<1, 256, 0, stream>>>(bcnt, bbase, offsets);
    k_bcsr<<<NBK, 256, 0, stream>>>(staging, bcnt, bbase, offsets, dinv, csr_src);

    // layer 1
    k_xw1<<<(NN + 3) / 4, 256, 0, stream>>>(x, W1, dinv, Ap2);
    k_gather<<<(NN * 64 + 255) / 256, 256, 0, stream>>>(Ap2, csr_src, offsets, dinv, B2);

    // layer 2
    k_layer2<<<(NN + 63) / 64, 256, 0, stream>>>(B2, b1, W2, dinv, Ap2);
    k_gather<<<(NN * 64 + 255) / 256, 256, 0, stream>>>(Ap2, csr_src, offsets, dinv, B2);

    // pool + head
    k_pool_init<<<(NG * HIDC + 255) / 256, 256, 0, stream>>>(pooled, cnt);
    k_pool<<<(NN + 63) / 64, 64, 0, stream>>>(B2, b2, batch, pooled, cnt);
    k_final<<<NG, 128, 0, stream>>>(pooled, cnt, Wc, bc, out);
}